// Round 5
// baseline (180.655 us; speedup 1.0000x reference)
//
#include <hip/hip_runtime.h>
#include <cstdint>
#include <cstddef>

// Problem constants (B, S, E, H, MAXLEN) = (2, 2048, 1024, 16, 2048)
constexpr int Sn = 2048;
constexpr int En = 1024;
constexpr int Bn = 2;
constexpr int Hn = 16;
constexpr int NCH = 32;            // chunks per batch (S/CHUNK)
constexpr int CHUNK = 64;
constexpr int Mtot = Bn * Sn;      // 4096
constexpr int GCH = Mtot / CHUNK;  // 64 global chunks

typedef __bf16 bf16x8 __attribute__((ext_vector_type(8)));
typedef float  f32x4  __attribute__((ext_vector_type(4)));

#define GLOBAL_AS(p) ((const __attribute__((address_space(1))) void*)(p))
#define LDS_AS(p)    ((__attribute__((address_space(3))) void*)(p))

__device__ __forceinline__ unsigned short f2bf(float f) {
    union { float f; uint32_t u; } v; v.f = f;
    const uint32_t u = v.u;
    return (unsigned short)((u + 0x7fffu + ((u >> 16) & 1u)) >> 16);  // RNE
}
__device__ __forceinline__ float bf2f_lo(uint32_t u) {
    union { uint32_t u; float f; } v; v.u = u << 16; return v.f;
}
__device__ __forceinline__ float bf2f_hi(uint32_t u) {
    union { uint32_t u; float f; } v; v.u = u & 0xffff0000u; return v.f;
}

// ---------------------------------------------------------------------------
// Fused fp32 -> bf16 cast of x (XN), Wv (WN), Wo (WN) in one launch.
// ---------------------------------------------------------------------------
constexpr int XN = Bn * Sn * En;   // 4194304
constexpr int WN = En * En;        // 1048576

__global__ __launch_bounds__(256)
void cast3(const float* __restrict__ x, const float* __restrict__ Wv,
           const float* __restrict__ Wo, unsigned short* __restrict__ xb,
           unsigned short* __restrict__ Wvb, unsigned short* __restrict__ Wob)
{
    const int i = (blockIdx.x * 256 + threadIdx.x) * 4;
    const float* src; unsigned short* dst; int off;
    if (i < XN)           { src = x;  dst = xb;  off = i; }
    else if (i < XN + WN) { src = Wv; dst = Wvb; off = i - XN; }
    else                  { src = Wo; dst = Wob; off = i - XN - WN; }
    const float4 v = *(const float4*)(src + off);
    ushort4 o;
    o.x = f2bf(v.x); o.y = f2bf(v.y); o.z = f2bf(v.z); o.w = f2bf(v.w);
    *(ushort4*)(dst + off) = o;
}

// ---------------------------------------------------------------------------
// bf16 MFMA GEMM (NT), split-K=2: P[ks][m,n] = sum_{k in split ks} A[m,k]*W[n,k].
// m97 wave shape: tile 128x128, 4 waves in 2x2 each computing 64x64 (4x4
// grid of 16x16x32 MFMAs), BK=64 -> 8 K-iters per block, 32 MFMA per wave
// per barrier pair, 0.5 KB LDS-read per MFMA (vs 0.75 for 64x32 waves).
// Grid (N/128, M/128, 2) = 512 blocks = 2 blocks/CU co-resident (the split-K
// z-dim is what keeps co-residency at N=1024).
// Staging: global_load_lds width=16 into MFMA-fragment-order LDS
// (1024 B chunk = 16 rows x 32 k; lane l -> row (l&15), k (l>>4)*8).
// Fragments read at chunk_base + lane*16 B -> conflict-free ds_read_b128.
// Output: raw fp32 partials, no bias/mask (folded into the reduce kernels).
// ---------------------------------------------------------------------------
__global__ __launch_bounds__(256)
void gemm_splitk(const unsigned short* __restrict__ A, const unsigned short* __restrict__ Bw,
                 float* __restrict__ Part, int M, int N, int K)
{
    __shared__ __align__(16) unsigned short As[128 * 64];  // 16 KB
    __shared__ __align__(16) unsigned short Bs[128 * 64];  // 16 KB

    const int tid  = threadIdx.x;
    const int lane = tid & 63;
    const int wv   = tid >> 6;      // wave 0..3
    const int wr   = wv >> 1;       // wave row (0..1) -> M
    const int wc   = wv & 1;        // wave col (0..1) -> N
    const int bm   = blockIdx.y * 128;
    const int bn   = blockIdx.x * 128;
    const int ks   = blockIdx.z;    // K-split 0..1
    const int m16  = lane & 15;
    const int kq   = lane >> 4;     // k-quarter (staging) / row-quad (C/D)

    const int kbase = ks * (K / 2);

    f32x4 acc[4][4] = {};

    // Wave wv stages A row-groups {2wv, 2wv+1} x k-halves {0,1}, B likewise.
    const int rg0 = 2 * wv, rg1 = 2 * wv + 1;
    const unsigned short* gA0 = A  + (size_t)(bm + 16 * rg0 + m16) * K + kbase + kq * 8;
    const unsigned short* gA1 = A  + (size_t)(bm + 16 * rg1 + m16) * K + kbase + kq * 8;
    const unsigned short* gB0 = Bw + (size_t)(bn + 16 * rg0 + m16) * K + kbase + kq * 8;
    const unsigned short* gB1 = Bw + (size_t)(bn + 16 * rg1 + m16) * K + kbase + kq * 8;
    unsigned short* lA00 = &As[(rg0 * 2 + 0) * 512];
    unsigned short* lA01 = &As[(rg0 * 2 + 1) * 512];
    unsigned short* lA10 = &As[(rg1 * 2 + 0) * 512];
    unsigned short* lA11 = &As[(rg1 * 2 + 1) * 512];
    unsigned short* lB00 = &Bs[(rg0 * 2 + 0) * 512];
    unsigned short* lB01 = &Bs[(rg0 * 2 + 1) * 512];
    unsigned short* lB10 = &Bs[(rg1 * 2 + 0) * 512];
    unsigned short* lB11 = &Bs[(rg1 * 2 + 1) * 512];

    for (int k0 = 0; k0 < K / 2; k0 += 64) {
        __syncthreads();   // previous iteration's frag reads done
        __builtin_amdgcn_global_load_lds(GLOBAL_AS(gA0 + k0),      LDS_AS(lA00), 16, 0, 0);
        __builtin_amdgcn_global_load_lds(GLOBAL_AS(gA0 + k0 + 32), LDS_AS(lA01), 16, 0, 0);
        __builtin_amdgcn_global_load_lds(GLOBAL_AS(gA1 + k0),      LDS_AS(lA10), 16, 0, 0);
        __builtin_amdgcn_global_load_lds(GLOBAL_AS(gA1 + k0 + 32), LDS_AS(lA11), 16, 0, 0);
        __builtin_amdgcn_global_load_lds(GLOBAL_AS(gB0 + k0),      LDS_AS(lB00), 16, 0, 0);
        __builtin_amdgcn_global_load_lds(GLOBAL_AS(gB0 + k0 + 32), LDS_AS(lB01), 16, 0, 0);
        __builtin_amdgcn_global_load_lds(GLOBAL_AS(gB1 + k0),      LDS_AS(lB10), 16, 0, 0);
        __builtin_amdgcn_global_load_lds(GLOBAL_AS(gB1 + k0 + 32), LDS_AS(lB11), 16, 0, 0);
        __syncthreads();   // implies vmcnt(0): staging landed

        bf16x8 af[4][2], bfr[4][2];
#pragma unroll
        for (int i = 0; i < 4; ++i)
#pragma unroll
            for (int kh = 0; kh < 2; ++kh) {
                af[i][kh]  = *(const bf16x8*)&As[(((wr * 4 + i) * 2) + kh) * 512 + lane * 8];
                bfr[i][kh] = *(const bf16x8*)&Bs[(((wc * 4 + i) * 2) + kh) * 512 + lane * 8];
            }
#pragma unroll
        for (int kh = 0; kh < 2; ++kh)
#pragma unroll
            for (int i = 0; i < 4; ++i)
#pragma unroll
                for (int j = 0; j < 4; ++j)
                    acc[i][j] = __builtin_amdgcn_mfma_f32_16x16x32_bf16(af[i][kh], bfr[j][kh], acc[i][j], 0, 0, 0);
    }

    // Epilogue: raw fp32 partial. C/D layout: col = lane&15, row = (lane>>4)*4+reg.
    float* P = Part + (size_t)ks * M * N;
#pragma unroll
    for (int i = 0; i < 4; ++i) {
        const int r0 = bm + wr * 64 + i * 16 + kq * 4;
#pragma unroll
        for (int j = 0; j < 4; ++j) {
            const int c0 = bn + wc * 64 + j * 16 + m16;
#pragma unroll
            for (int r = 0; r < 4; ++r)
                P[(size_t)(r0 + r) * N + c0] = acc[i][j][r];
        }
    }
}

// ---------------------------------------------------------------------------
// reduce1: vm = mask ? (P0 + P1 + bv) : 0 (bf16), fused per-chunk column sums.
// grid (En/256, GCH); thread = column e, loops the 64 rows of global chunk g.
// ---------------------------------------------------------------------------
__global__ __launch_bounds__(256)
void reduce1(const float* __restrict__ Part, const float* __restrict__ bv,
             const int* __restrict__ mask, unsigned short* __restrict__ vmb,
             float* __restrict__ csum)
{
    const int e = blockIdx.x * 256 + threadIdx.x;
    const int g = blockIdx.y;
    const float bias = bv[e];
    const float* P0 = Part;
    const float* P1 = Part + (size_t)Mtot * En;
    float s = 0.0f;
    const int row0 = g * CHUNK;
    for (int r = 0; r < CHUNK; ++r) {
        const int row = row0 + r;
        const size_t off = (size_t)row * En + e;
        float v = P0[off] + P1[off] + bias;
        v = (mask[row] == 0) ? 0.0f : v;
        s += v;
        vmb[off] = f2bf(v);
    }
    csum[(size_t)g * En + e] = s;
}

// ---------------------------------------------------------------------------
// reduce2: out = P0 + P1 + bo (fp32), float4.
// ---------------------------------------------------------------------------
__global__ __launch_bounds__(256)
void reduce2(const float* __restrict__ Part, const float* __restrict__ bo,
             float* __restrict__ out)
{
    const size_t i = ((size_t)blockIdx.x * 256 + threadIdx.x) * 4;
    const float4 p0 = *(const float4*)(Part + i);
    const float4 p1 = *(const float4*)(Part + (size_t)Mtot * En + i);
    const float4 bb = *(const float4*)(bo + (i & (En - 1)));
    float4 o;
    o.x = p0.x + p1.x + bb.x; o.y = p0.y + p1.y + bb.y;
    o.z = p0.z + p1.z + bb.z; o.w = p0.w + p1.w + bb.w;
    *(float4*)(out + i) = o;
}

// ---------------------------------------------------------------------------
// combine: inline exclusive scan of csum (32 values per column) + within-chunk
// prefix + weighted combine -> opre (bf16).
// out_pre[b,i,e] = (w2*Pref[i&~1] + (i odd)*w1*vm[i-1] + w0*(T - Pref[i])) / Z
// Z = (i&~1)*w2 + (i odd)*w1 + (S-i)*w0 + 1e-8   (pre-mask normalization)
// 2 columns/thread (same head since e is even and dh=64).
// ---------------------------------------------------------------------------
__global__ __launch_bounds__(256)
void combine(const unsigned short* __restrict__ vm, const float* __restrict__ csum,
             const float* __restrict__ hier, unsigned short* __restrict__ opre)
{
    const int ep = blockIdx.x * 256 + threadIdx.x;
    const int e = ep * 2;
    const int c = blockIdx.y;
    const int b = blockIdx.z;
    const int h = e >> 6;   // dh = 64

    const float w0 = hier[((size_t)b * Hn + h) * 3 + 0];
    const float w1 = hier[((size_t)b * Hn + h) * 3 + 1] * 0.5f;
    const float w2 = hier[((size_t)b * Hn + h) * 3 + 2] * 0.25f;

    // Inline scan over this batch's 32 chunk sums.
    float run0 = 0.0f, run1 = 0.0f, T0 = 0.0f, T1 = 0.0f;
    const int g0 = b * NCH;
    for (int c2 = 0; c2 < NCH; ++c2) {
        const size_t off = (size_t)(g0 + c2) * En + e;
        const float v0 = csum[off], v1 = csum[off + 1];
        if (c2 < c) { run0 += v0; run1 += v1; }
        T0 += v0; T1 += v1;
    }

    float prev0 = 0.0f, prev1 = 0.0f;
    const size_t base = ((size_t)b * Sn + c * CHUNK) * En + e;

    for (int t = 0; t < CHUNK; ++t) {
        const int i = c * CHUNK + t;
        const uint32_t u = *(const uint32_t*)(vm + base + (size_t)t * En);
        const float cur0 = bf2f_lo(u), cur1 = bf2f_hi(u);
        float num0, num1, Z;
        if (i & 1) {
            num0 = w2 * (run0 - prev0) + w1 * prev0 + w0 * (T0 - run0);
            num1 = w2 * (run1 - prev1) + w1 * prev1 + w0 * (T1 - run1);
            Z = (float)(i - 1) * w2 + w1 + (float)(Sn - i) * w0 + 1e-8f;
        } else {
            num0 = w2 * run0 + w0 * (T0 - run0);
            num1 = w2 * run1 + w0 * (T1 - run1);
            Z = (float)i * w2 + (float)(Sn - i) * w0 + 1e-8f;
        }
        const float rz = 1.0f / Z;
        const uint32_t o = (uint32_t)f2bf(num0 * rz) | ((uint32_t)f2bf(num1 * rz) << 16);
        *(uint32_t*)(opre + base + (size_t)t * En) = o;
        run0 += cur0; run1 += cur1;
        prev0 = cur0; prev1 = cur1;
    }
}

// ---------------------------------------------------------------------------
extern "C" void kernel_launch(void* const* d_in, const int* in_sizes, int n_in,
                              void* d_out, int out_size, void* d_ws, size_t ws_size,
                              hipStream_t stream)
{
    // 0:x 1:attention_mask 2:level_indices 3:Wq 4:bq 5:Wk 6:bk 7:Wv 8:bv 9:hier 10:Wo 11:bo
    const float* x    = (const float*)d_in[0];
    const int*   mask = (const int*)d_in[1];
    const float* Wv   = (const float*)d_in[7];
    const float* bv   = (const float*)d_in[8];
    const float* hier = (const float*)d_in[9];
    const float* Wo   = (const float*)d_in[10];
    const float* bo   = (const float*)d_in[11];
    float* out = (float*)d_out;

    const int M = Mtot, N = En, K = En;

    char* ws = (char*)d_ws;
    unsigned short* xb    = (unsigned short*)ws;  ws += (size_t)M * K * 2;        // 8 MB
    unsigned short* Wvb   = (unsigned short*)ws;  ws += (size_t)N * K * 2;        // 2 MB
    unsigned short* Wob   = (unsigned short*)ws;  ws += (size_t)N * K * 2;        // 2 MB
    unsigned short* vmb   = (unsigned short*)ws;  ws += (size_t)M * N * 2;        // 8 MB
    float*          csum  = (float*)ws;           ws += (size_t)GCH * En * 4;     // 256 KB
    unsigned short* opreb = (unsigned short*)ws;  ws += (size_t)M * N * 2;        // 8 MB
    float*          Part  = (float*)ws;           ws += (size_t)2 * M * N * 4;    // 32 MB

    dim3 threads(256);

    // Fused casts to bf16 (x, Wv, Wo)
    cast3<<<dim3((XN + 2 * WN) / 1024), threads, 0, stream>>>(x, Wv, Wo, xb, Wvb, Wob);

    dim3 gemm_grid(N / 128, M / 128, 2);   // (8, 32, 2) = 512 blocks = 2/CU

    // 1) partials of x @ Wv.T (split-K)
    gemm_splitk<<<gemm_grid, threads, 0, stream>>>(xb, Wvb, Part, M, N, K);
    // 2) vm = mask ? (P0+P1+bv) : 0 (bf16) + per-chunk column sums
    reduce1<<<dim3(En / 256, GCH), threads, 0, stream>>>(Part, bv, mask, vmb, csum);
    // 3) weighted combine (inline csum scan) -> opre (bf16)
    combine<<<dim3(En / 512, NCH, Bn), threads, 0, stream>>>(vmb, csum, hier, opreb);
    // 4) partials of opre @ Wo.T (split-K)
    gemm_splitk<<<gemm_grid, threads, 0, stream>>>(opreb, Wob, Part, M, N, K);
    // 5) out = P0 + P1 + bo
    reduce2<<<dim3((M * N) / 1024), threads, 0, stream>>>(Part, bo, out);
}